// Round 14
// baseline (226.188 us; speedup 1.0000x reference)
//
#include <hip/hip_runtime.h>
#include <math.h>

#define SEQ 197
#define EMB 768
#define NH  12
#define HD  64
#define NE  28
#define SK  208
#define VP  232
#define PP  232
#define EP  232
#define HP  68
#define TP  66
#define NW  7
#define NT  448

typedef __attribute__((ext_vector_type(8))) __bf16 bf16x8;
typedef __attribute__((ext_vector_type(4))) float  f32x4;

__device__ __forceinline__ unsigned short f2bf(float f) {
    unsigned u = __float_as_uint(f);
    u += 0x7fffu + ((u >> 16) & 1u);
    return (unsigned short)(u >> 16);
}
__device__ __forceinline__ float bfl(unsigned u) { return __uint_as_float(u << 16); }

__device__ __forceinline__ void gl_lds16(const ushort* g, ushort* l) {
    __builtin_amdgcn_global_load_lds(
        (const __attribute__((address_space(1))) unsigned int*)g,
        (__attribute__((address_space(3))) unsigned int*)l, 16, 0, 0);
}

// ---------------------------------------------------------------------------
// prep kernels (unchanged)
// ---------------------------------------------------------------------------
__global__ void cvt_k(const float* __restrict__ src, ushort* __restrict__ dst, int n4) {
    int i = blockIdx.x * 256 + threadIdx.x;
    if (i < n4) {
        float4 v = ((const float4*)src)[i];
        ushort4 o = { f2bf(v.x), f2bf(v.y), f2bf(v.z), f2bf(v.w) };
        ((ushort4*)dst)[i] = o;
    }
}

__global__ void cvt_w4(const float* __restrict__ wq, const float* __restrict__ wk,
                       const float* __restrict__ wv, const float* __restrict__ wo,
                       ushort* __restrict__ wqkv, ushort* __restrict__ wob) {
    int i = blockIdx.x * 256 + threadIdx.x;
    if (i >= 4 * 147456) return;
    int seg = i / 147456, r = i - seg * 147456;
    const float* s = (seg == 0) ? wq : (seg == 1) ? wk : (seg == 2) ? wv : wo;
    float4 v = ((const float4*)s)[r];
    ushort4 o = { f2bf(v.x), f2bf(v.y), f2bf(v.z), f2bf(v.w) };
    if (seg < 3) ((ushort4*)wqkv)[(size_t)seg * 147456 + r] = o;
    else         ((ushort4*)wob)[r] = o;
}

__global__ void wr_prep(const float* __restrict__ wq,
                        const float* __restrict__ qtx, const float* __restrict__ qty,
                        ushort* __restrict__ wqkv) {
    int i = blockIdx.x * 256 + threadIdx.x;
    if (i >= 768 * 768) return;
    int row2 = i / 768, c = i - row2 * 768;
    ushort* dst = wqkv + (size_t)(2304 + row2) * EMB + c;
    if (row2 >= 672) { *dst = 0; return; }
    int h = row2 / 56, j = row2 - h * 56;
    const int off = (j < 28) ? 0 : 32;
    const float* tab = (j < 28) ? (qtx + j * 32) : (qty + (j - 28) * 32);
    float acc = 0.f;
#pragma unroll
    for (int d = 0; d < 32; d++)
        acc += wq[(size_t)(h * 64 + off + d) * EMB + c] * tab[d];
    *dst = f2bf(acc);
}

__global__ void rbias_k(const float* __restrict__ bq,
                        const float* __restrict__ qtx, const float* __restrict__ qty,
                        float* __restrict__ rb) {
    int i = blockIdx.x * 256 + threadIdx.x;
    if (i >= 672) return;
    int h = i / 56, j = i - h * 56;
    const int off = (j < 28) ? 0 : 32;
    const float* tab = (j < 28) ? (qtx + j * 32) : (qty + (j - 28) * 32);
    float acc = 0.f;
#pragma unroll
    for (int d = 0; d < 32; d++)
        acc += bq[h * 64 + off + d] * tab[d];
    rb[i] = acc;
}

// ---------------------------------------------------------------------------
// 8-phase 256x256 bf16 GEMM (T2 swizzle + T3/T4 counted vmcnt + T5 setprio).
// MODE-0 semantics only: A (M x 768) x W rows (3072 x 768) -> qkv scatter +
// rel region. 512 thr = 8 waves (2M x 4N); BK=64; LDS 128 KiB (2 dbuf x
// {A,B} x 2 halves x 128x64 bf16). st_16x32: within each 16x32 subtile,
// col bit4 ^= row bit3; staged via linear gl_lds dest + inverse-swizzled
// global source; read with swizzled offsets. Half-tiles {B0,B1,A0,A1} staged
// 7 ahead; vmcnt(6) before the K-tile-closing barrier (race-safe placement);
// vmcnt(0) at tail only.
// ---------------------------------------------------------------------------
__global__ __launch_bounds__(512, 2) void gemm256(
    const ushort* __restrict__ A, const ushort* __restrict__ W,
    const float* __restrict__ b0, const float* __restrict__ b1, const float* __restrict__ b2,
    const float* __restrict__ rbias,
    ushort* __restrict__ q_o, ushort* __restrict__ k_o, ushort* __restrict__ v_o,
    ushort* __restrict__ r_o, int M)
{
    __shared__ __align__(16) ushort Lds[2][2][2][8192];   // [buf][A0/B1][half][128x64]

    const int tid  = threadIdx.x;
    const int w    = tid >> 6, lane = tid & 63;
    const int wr   = w >> 2,  wc   = w & 3;

    // XCD-chunked swizzle (bijective incl. tail group)
    const int nmt = gridDim.x, nnt = gridDim.y;
    const int lin = blockIdx.y * nmt + blockIdx.x;
    const int gsz = 8 * nnt;
    const int grp = lin / gsz;
    const int rr  = lin - grp * gsz;
    int mig = nmt - grp * 8; if (mig > 8) mig = 8;
    const int mt  = grp * 8 + rr % mig;
    const int nt  = rr / mig;
    const int m0  = mt * 256;
    const int n0  = nt * 256;

    // staging source precompute (inverse swizzle of linear dest)
    int rowl[2], csrcl[2];
#pragma unroll
    for (int l = 0; l < 2; l++) {
        const int o  = (l * 512 + tid) * 8;          // ushort offset of this 16B
        const int R  = o >> 10, C = (o >> 9) & 1;
        const int ir = (o >> 5) & 15;
        const int cd = o & 31;                        // 0,8,16,24
        rowl[l]  = R * 16 + ir;
        csrcl[l] = (C << 5) + (cd ^ ((rowl[l] & 8) << 1));
    }
    // ds_read lane base (swizzled)
    const int base_a = (lane & 15) * 32 + (((lane >> 4) << 3) ^ ((lane & 8) << 1));

    f32x4 acc[8][4];
#pragma unroll
    for (int mf = 0; mf < 8; mf++)
#pragma unroll
        for (int nf = 0; nf < 4; nf++) acc[mf][nf] = (f32x4)0.f;

    const int NKT = EMB / 64;   // 12 K-tiles

    auto STAGE = [&](int T, int j) {
        const int buf = T & 1, kk0 = T * 64;
        if (j < 2) {            // B half j
            ushort* dbase = &Lds[buf][1][j][0];
#pragma unroll
            for (int l = 0; l < 2; l++)
                gl_lds16(W + (size_t)(n0 + j * 128 + rowl[l]) * EMB + kk0 + csrcl[l],
                         dbase + l * 4096 + w * 512);
        } else {                // A half j-2
            ushort* dbase = &Lds[buf][0][j - 2][0];
#pragma unroll
            for (int l = 0; l < 2; l++) {
                int rrow = m0 + (j - 2) * 128 + rowl[l];
                if (rrow >= M) rrow = M - 1;
                gl_lds16(A + (size_t)rrow * EMB + kk0 + csrcl[l],
                         dbase + l * 4096 + w * 512);
            }
        }
    };

    // prologue: 7 half-tiles (K-tile0 all + K-tile1 B0,B1,A0)
#pragma unroll
    for (int H = 0; H < 7; H++) STAGE(H >> 2, H & 3);
    asm volatile("s_waitcnt vmcnt(6)" ::: "memory");
    asm volatile("s_barrier" ::: "memory");

    for (int t = 0; t < NKT; ++t) {
        const int buf = t & 1;
        const ushort* Ah = &Lds[buf][0][wr][0];
        const ushort* Bh = &Lds[buf][1][wc >> 1][0];
        bf16x8 bfr[4][2];
#pragma unroll
        for (int p = 0; p < 4; ++p) {
            if (p == 0) {
#pragma unroll
                for (int nf = 0; nf < 4; ++nf)
#pragma unroll
                    for (int ks = 0; ks < 2; ++ks)
                        bfr[nf][ks] = *(const bf16x8*)&Bh[(((((wc & 1) * 4 + nf) * 2) + ks) << 9) + base_a];
            }
            bf16x8 afr[2][2];
#pragma unroll
            for (int mi = 0; mi < 2; ++mi)
#pragma unroll
                for (int ks = 0; ks < 2; ++ks)
                    afr[mi][ks] = *(const bf16x8*)&Ah[((((p * 2 + mi) * 2) + ks) << 9) + base_a];

            const int H = 4 * t + p + 7;
            if (H < 4 * NKT) STAGE(H >> 2, H & 3);

            asm volatile("s_barrier" ::: "memory");
            asm volatile("s_waitcnt lgkmcnt(0)" ::: "memory");
            __builtin_amdgcn_sched_barrier(0);
            __builtin_amdgcn_s_setprio(1);
#pragma unroll
            for (int mi = 0; mi < 2; ++mi)
#pragma unroll
                for (int nf = 0; nf < 4; ++nf)
#pragma unroll
                    for (int ks = 0; ks < 2; ++ks)
                        acc[p * 2 + mi][nf] = __builtin_amdgcn_mfma_f32_16x16x32_bf16(
                            afr[mi][ks], bfr[nf][ks], acc[p * 2 + mi][nf], 0, 0, 0);
            __builtin_amdgcn_s_setprio(0);
            __builtin_amdgcn_sched_barrier(0);
            if (p == 3 && t < NKT - 1) {
                if (t == NKT - 2) asm volatile("s_waitcnt vmcnt(0)" ::: "memory");
                else              asm volatile("s_waitcnt vmcnt(6)" ::: "memory");
            }
            asm volatile("s_barrier" ::: "memory");
        }
    }

    // epilogue: C scatter (MODE-0 semantics)
    const int mat = n0 / EMB;
    const int nr  = n0 - mat * EMB;
    const float* bias = (mat == 0) ? b0 : (mat == 1) ? b1 : b2;
    ushort* dst = (mat == 0) ? q_o : (mat == 1) ? k_o : v_o;

#pragma unroll
    for (int mf = 0; mf < 8; ++mf) {
#pragma unroll
        for (int r = 0; r < 4; ++r) {
            const int gm = m0 + wr * 128 + mf * 16 + (lane >> 4) * 4 + r;
            if (gm >= M) continue;
            const int bb = gm / SEQ, ss = gm - bb * SEQ;
#pragma unroll
            for (int nf = 0; nf < 4; ++nf) {
                const int cl = wc * 64 + nf * 16 + (lane & 15);
                const float v = acc[mf][nf][r];
                if (mat < 3) {
                    const int col = nr + cl;
                    dst[(((size_t)bb * NH + (col >> 6)) * SEQ + ss) * HD + (col & 63)] =
                        f2bf(v + bias[col]);
                } else {
                    const int col2 = nr - 2304 + n0 - n0 + cl + (n0 - 2304 - nr); // = (n0-2304)+cl
                    const int c2 = (n0 - 2304) + cl;
                    if (c2 < 672) {
                        const int h2 = c2 / 56, j = c2 - h2 * 56;
                        r_o[((size_t)(bb * NH + h2) * SEQ + ss) * 56 + j] = f2bf(v + rbias[c2]);
                    }
                    (void)col2;
                }
            }
        }
    }
}

// ---------------------------------------------------------------------------
// 128x128 m97-pattern GEMM — retained for MODE 1 (output projection).
// ---------------------------------------------------------------------------
__global__ __launch_bounds__(256, 2) void mfma_gemm1(
    const ushort* __restrict__ A, const ushort* __restrict__ W,
    const float* __restrict__ b0, float* __restrict__ f_o, int M)
{
    __shared__ __align__(16) ushort As[128 * 32];
    __shared__ __align__(16) ushort Bs[128 * 32];

    const int tid  = threadIdx.x;
    const int w    = tid >> 6, lane = tid & 63;
    const int wr   = w >> 1,  wc   = w & 1;

    const int nmt = gridDim.x, nnt = gridDim.y;
    const int lin = blockIdx.y * nmt + blockIdx.x;
    const int gsz = 8 * nnt;
    const int grp = lin / gsz;
    const int rr  = lin - grp * gsz;
    int mig = nmt - grp * 8; if (mig > 8) mig = 8;
    const int mt  = grp * 8 + rr % mig;
    const int nt  = rr / mig;
    const int m0  = mt * 128;
    const int n0  = nt * 128;

    const int srow = tid >> 2;
    const int skb  = (tid & 3) * 8;

    f32x4 acc[4][4];
#pragma unroll
    for (int m = 0; m < 4; m++)
#pragma unroll
        for (int n = 0; n < 4; n++) acc[m][n] = (f32x4)0.f;

    int ra0 = m0 + srow;       if (ra0 >= M) ra0 = M - 1;
    int ra1 = m0 + 64 + srow;  if (ra1 >= M) ra1 = M - 1;
    const int rb0 = n0 + srow, rb1 = n0 + 64 + srow;

    for (int k0 = 0; k0 < EMB; k0 += 32) {
        gl_lds16(A + (size_t)ra0 * EMB + k0 + skb, As + (w * 512));
        gl_lds16(A + (size_t)ra1 * EMB + k0 + skb, As + (2048 + w * 512));
        gl_lds16(W + (size_t)rb0 * EMB + k0 + skb, Bs + (w * 512));
        gl_lds16(W + (size_t)rb1 * EMB + k0 + skb, Bs + (2048 + w * 512));
        __syncthreads();

        bf16x8 af[4], bfr[4];
#pragma unroll
        for (int m = 0; m < 4; m++)
            af[m] = *(const bf16x8*)&As[(wr * 64 + m * 16 + (lane & 15)) * 32 + (lane >> 4) * 8];
#pragma unroll
        for (int n = 0; n < 4; n++)
            bfr[n] = *(const bf16x8*)&Bs[(wc * 64 + n * 16 + (lane & 15)) * 32 + (lane >> 4) * 8];
#pragma unroll
        for (int m = 0; m < 4; m++)
#pragma unroll
            for (int n = 0; n < 4; n++)
                acc[m][n] = __builtin_amdgcn_mfma_f32_16x16x32_bf16(af[m], bfr[n], acc[m][n], 0, 0, 0);
        __syncthreads();
    }

#pragma unroll
    for (int m = 0; m < 4; m++) {
#pragma unroll
        for (int r = 0; r < 4; r++) {
            const int gm = m0 + wr * 64 + m * 16 + (lane >> 4) * 4 + r;
            if (gm >= M) continue;
#pragma unroll
            for (int n = 0; n < 4; n++) {
                const int col = n0 + wc * 64 + n * 16 + (lane & 15);
                f_o[(size_t)gm * EMB + col] = acc[m][n][r] + b0[col];
            }
        }
    }
}

// ---------------------------------------------------------------------------
// MFMA fused attention (r12 one-hot factorization) — unchanged.
// ---------------------------------------------------------------------------
__global__ __launch_bounds__(NT) void attn_mfma(
    const ushort* __restrict__ xq, const ushort* __restrict__ xk, const ushort* __restrict__ xv,
    const ushort* __restrict__ rxy_g,
    const float* __restrict__ v_tab_x, const float* __restrict__ v_tab_y,
    const int* __restrict__ x_dist, const int* __restrict__ y_dist,
    ushort* __restrict__ ao)
{
    __shared__ __align__(16) ushort K_s[SK * HD];
    __shared__ __align__(16) ushort EXYs_s[SK * 40];
    __shared__ __align__(16) ushort EXYT_s[32 * EP];
    __shared__ __align__(16) ushort VT_s[HD * VP];
    __shared__ __align__(16) ushort P_s[NW * 16 * PP];
    __shared__ __align__(16) ushort vt_s[HD * TP];
    __shared__ __align__(16) ushort h_s[NW][16][HP];

    const int bh = blockIdx.x;
    const int b  = bh / NH;
    const int h  = bh % NH;
    const size_t base = (size_t)bh * SEQ * HD;
    const ushort* __restrict__ rxy_b = rxy_g + (size_t)bh * SEQ * 56;
    const int tid = threadIdx.x;
    const int w = tid >> 6, lane = tid & 63;
    const int g = lane >> 4, c15 = lane & 15;

    for (int idx = tid; idx < SK * 8; idx += NT) {
        const int r = idx >> 3, c = idx & 7;
        uint4 v = make_uint4(0, 0, 0, 0);
        if (r < SEQ) v = *(const uint4*)(xk + base + r * HD + c * 8);
        *(uint4*)&K_s[r * HD + ((c ^ (r & 7)) << 3)] = v;
    }
    for (int idx = tid; idx < SK * 40 / 8; idx += NT)
        *(uint4*)&EXYs_s[idx * 8] = make_uint4(0, 0, 0, 0);
    for (int idx = tid; idx < 32 * EP / 8; idx += NT)
        *(uint4*)&EXYT_s[idx * 8] = make_uint4(0, 0, 0, 0);
    for (int idx = tid; idx < HD * (VP - SEQ); idx += NT) {
        const int d = idx / (VP - SEQ), k = SEQ + idx - d * (VP - SEQ);
        VT_s[d * VP + k] = 0;
    }
    for (int idx = tid; idx < NW * 16 * PP / 8; idx += NT)
        *(uint4*)&P_s[idx * 8] = make_uint4(0, 0, 0, 0);
    for (int idx = tid; idx < 16 * 8 * 13; idx += NT) {
        const int kq = idx & 15, t = idx >> 4;
        const int db = t & 7, kh = t >> 3;
        const int k = kh * 16 + kq;
        if (k >= SEQ) continue;
        uint4 v = *(const uint4*)(xv + base + k * HD + db * 8);
        ushort* col = &VT_s[(db * 8) * VP + k];
        col[0 * VP] = (ushort)(v.x); col[1 * VP] = (ushort)(v.x >> 16);
        col[2 * VP] = (ushort)(v.y); col[3 * VP] = (ushort)(v.y >> 16);
        col[4 * VP] = (ushort)(v.z); col[5 * VP] = (ushort)(v.z >> 16);
        col[6 * VP] = (ushort)(v.w); col[7 * VP] = (ushort)(v.w >> 16);
    }
    for (int idx = tid; idx < HD * 64; idx += NT) {
        const int d = idx >> 6, e = idx & 63;
        float v = 0.f;
        if (d < 32) { if (e < 28) v = v_tab_x[e * 32 + d]; }
        else        { if (e >= 28 && e < 56) v = v_tab_y[(e - 28) * 32 + (d - 32)]; }
        vt_s[d * TP + e] = f2bf(v);
    }
    __syncthreads();
    for (int k = tid; k < SEQ; k += NT) {
        const int cx = (k == 0) ? 14 : (x_dist[SEQ + k] - 14);
        const int cy = (k == 0) ? 14 : (y_dist[SEQ + k] - 14);
        const ushort one = 0x3f80;
        EXYs_s[k * 40 + cx]        = one;
        EXYs_s[k * 40 + 16 + cy]   = one;
        EXYT_s[cx * EP + k]        = one;
        EXYT_s[(16 + cy) * EP + k] = one;
    }
    __syncthreads();

    for (int qt = w; qt < 13; qt += NW) {
        const int qrow = qt * 16 + c15;
        const int qld  = (qrow < SEQ) ? qrow : (SEQ - 1);
        const bf16x8 qa0 = *(const bf16x8*)(xq + base + (size_t)qld * HD + g * 8);
        const bf16x8 qa1 = *(const bf16x8*)(xq + base + (size_t)qld * HD + 32 + g * 8);

        uint4 up;
        {
            const ushort* rrow = rxy_b + qld * 56;
            const int cxq = (qld > 0) ? (x_dist[SEQ + qld] - 14) : 0;
            const int cyq = (qld > 0) ? (y_dist[SEQ + qld] - 14) : 0;
            unsigned uu[4] = {0, 0, 0, 0};
#pragma unroll
            for (int j = 0; j < 8; j++) {
                const int c = g * 8 + j;
                ushort v;
                if (qld == 0)      v = (c == 15 || c == 31) ? (ushort)0 : rrow[(c < 16) ? 0 : 28];
                else if (c < 14)   v = rrow[c - cxq + 14];
                else if (c == 14)  v = rrow[0];
                else if (c == 15)  v = 0;
                else if (c < 30)   v = rrow[28 + (c - 16) - cyq + 14];
                else if (c == 30)  v = rrow[28];
                else               v = 0;
                uu[j >> 1] |= ((unsigned)v) << ((j & 1) * 16);
            }
            up.x = uu[0]; up.y = uu[1]; up.z = uu[2]; up.w = uu[3];
        }
        const bf16x8 qa2 = *(bf16x8*)&up;

        {
            uint4* hz = (uint4*)h_s[w];
            for (int i = lane; i < 16 * HP / 8; i += 64) hz[i] = make_uint4(0, 0, 0, 0);
        }

        const int q4 = qt * 16 + 4 * g;
        float sum[4] = {0.f, 0.f, 0.f, 0.f};

#pragma unroll
        for (int kt = 0; kt < 13; kt++) {
            const int kr = kt * 16 + c15;
            bf16x8 kf0 = *(const bf16x8*)&K_s[kr * HD + (((0 + g) ^ (kr & 7)) << 3)];
            bf16x8 kf1 = *(const bf16x8*)&K_s[kr * HD + (((4 + g) ^ (kr & 7)) << 3)];
            bf16x8 kf2 = *(const bf16x8*)&EXYs_s[kr * 40 + g * 8];
            f32x4 a = (f32x4)0.f;
            a = __builtin_amdgcn_mfma_f32_16x16x32_bf16(qa0, kf0, a, 0, 0, 0);
            a = __builtin_amdgcn_mfma_f32_16x16x32_bf16(qa1, kf1, a, 0, 0, 0);
            a = __builtin_amdgcn_mfma_f32_16x16x32_bf16(qa2, kf2, a, 0, 0, 0);
#pragma unroll
            for (int r = 0; r < 4; r++) {
                const float l = a[r] * 0.125f - 8.0f;
                const float p = (kr < SEQ) ? __expf(l) : 0.f;
                sum[r] += p;
                P_s[(w * 16 + 4 * g + r) * PP + kr] = f2bf(p);
            }
        }
        float inv[4];
#pragma unroll
        for (int r = 0; r < 4; r++) {
            sum[r] += __shfl_xor(sum[r], 1);
            sum[r] += __shfl_xor(sum[r], 2);
            sum[r] += __shfl_xor(sum[r], 4);
            sum[r] += __shfl_xor(sum[r], 8);
            inv[r] = 1.f / sum[r];
        }

        f32x4 px0 = (f32x4)0.f, px1 = (f32x4)0.f;
#pragma unroll
        for (int ks = 0; ks < 7; ks++) {
            bf16x8 pf = *(const bf16x8*)&P_s[(w * 16 + c15) * PP + ks * 32 + g * 8];
            bf16x8 e0 = *(const bf16x8*)&EXYT_s[c15 * EP + ks * 32 + g * 8];
            bf16x8 e1 = *(const bf16x8*)&EXYT_s[(16 + c15) * EP + ks * 32 + g * 8];
            px0 = __builtin_amdgcn_mfma_f32_16x16x32_bf16(pf, e0, px0, 0, 0, 0);
            px1 = __builtin_amdgcn_mfma_f32_16x16x32_bf16(pf, e1, px1, 0, 0, 0);
        }

        float sx = px0[0], sy = px1[0];
        if (qt == 0) {
            sx += __shfl_xor(sx, 1); sx += __shfl_xor(sx, 2);
            sx += __shfl_xor(sx, 4); sx += __shfl_xor(sx, 8);
            sy += __shfl_xor(sy, 1); sy += __shfl_xor(sy, 2);
            sy += __shfl_xor(sy, 4); sy += __shfl_xor(sy, 8);
        }

#pragma unroll
        for (int r = 0; r < 4; r++) {
            const int q = q4 + r;
            if (q >= SEQ) continue;
            const int ql = 4 * g + r;
            if (q == 0) {
                if (c15 == 14) { h_s[w][ql][0] = f2bf(sx); h_s[w][ql][28] = f2bf(sy); }
            } else {
                const int cxq2 = x_dist[SEQ + q] - 14;
                const int cyq2 = y_dist[SEQ + q] - 14;
                if (c15 < 14) {
                    h_s[w][ql][c15 - cxq2 + 14]      = f2bf(px0[r]);
                    h_s[w][ql][28 + c15 - cyq2 + 14] = f2bf(px1[r]);
                } else if (c15 == 14) {
                    h_s[w][ql][0]  = f2bf(px0[r]);
                    h_s[w][ql][28] = f2bf(px1[r]);
                }
            }
        }

        f32x4 o[4];
#pragma unroll
        for (int dt = 0; dt < 4; dt++) o[dt] = (f32x4)0.f;
#pragma unroll
        for (int ks = 0; ks < 7; ks++) {
            bf16x8 pf = *(const bf16x8*)&P_s[(w * 16 + c15) * PP + ks * 32 + g * 8];
#pragma unroll
            for (int dt = 0; dt < 4; dt++) {
                bf16x8 vf = *(const bf16x8*)&VT_s[(dt * 16 + c15) * VP + ks * 32 + g * 8];
                o[dt] = __builtin_amdgcn_mfma_f32_16x16x32_bf16(pf, vf, o[dt], 0, 0, 0);
            }
        }
#pragma unroll
        for (int ks2 = 0; ks2 < 2; ks2++) {
            bf16x8 hf = *(const bf16x8*)&h_s[w][c15][ks2 * 32 + g * 8];
#pragma unroll
            for (int dt = 0; dt < 4; dt++) {
                bf16x8 tf = *(const bf16x8*)&vt_s[(dt * 16 + c15) * TP + ks2 * 32 + g * 8];
                o[dt] = __builtin_amdgcn_mfma_f32_16x16x32_bf16(hf, tf, o[dt], 0, 0, 0);
            }
        }

#pragma unroll
        for (int dt = 0; dt < 4; dt++) {
            const int d = dt * 16 + c15;
#pragma unroll
            for (int r = 0; r < 4; r++) {
                const int q = q4 + r;
                if (q < SEQ)
                    ao[((size_t)(b * SEQ + q)) * EMB + h * HD + d] = f2bf(o[dt][r] * inv[r]);
            }
        }
    }
}

extern "C" void kernel_launch(void* const* d_in, const int* in_sizes, int n_in,
                              void* d_out, int out_size, void* d_ws, size_t ws_size,
                              hipStream_t stream) {
    const float* x       = (const float*)d_in[0];
    const float* Wq      = (const float*)d_in[1];
    const float* bq      = (const float*)d_in[2];
    const float* Wk      = (const float*)d_in[3];
    const float* bk      = (const float*)d_in[4];
    const float* Wv      = (const float*)d_in[5];
    const float* bv      = (const float*)d_in[6];
    const float* Wo      = (const float*)d_in[7];
    const float* bo      = (const float*)d_in[8];
    const float* q_tab_x = (const float*)d_in[9];
    const float* q_tab_y = (const float*)d_in[10];
    const float* v_tab_x = (const float*)d_in[11];
    const float* v_tab_y = (const float*)d_in[12];
    const int*   x_dist  = (const int*)d_in[13];
    const int*   y_dist  = (const int*)d_in[14];
    float* out = (float*)d_out;

    const int M  = in_sizes[0] / EMB;   // 12608
    const int Bc = M / SEQ;             // 64

    ushort* xb   = (ushort*)d_ws;
    ushort* wqkv = xb   + (size_t)M * EMB;
    ushort* wob  = wqkv + (size_t)3072 * EMB;
    ushort* xqb  = wob  + (size_t)EMB * EMB;
    ushort* xkb  = xqb  + (size_t)M * EMB;
    ushort* xvb  = xkb  + (size_t)M * EMB;
    ushort* aob  = xvb  + (size_t)M * EMB;
    ushort* r_o  = aob  + (size_t)M * EMB;
    float*  rbia = (float*)(r_o + (size_t)Bc * NH * SEQ * 56);

    const int n4x = M * EMB / 4;
    cvt_k<<<dim3((n4x + 255) / 256), dim3(256), 0, stream>>>(x, xb, n4x);
    cvt_w4<<<dim3(2304), dim3(256), 0, stream>>>(Wq, Wk, Wv, Wo, wqkv, wob);
    wr_prep<<<dim3(2304), dim3(256), 0, stream>>>(Wq, q_tab_x, q_tab_y, wqkv);
    rbias_k<<<dim3(3), dim3(256), 0, stream>>>(bq, q_tab_x, q_tab_y, rbia);

    gemm256<<<dim3((M + 255) / 256, 12), dim3(512), 0, stream>>>(
        xb, wqkv, bq, bk, bv, rbia, xqb, xkb, xvb, r_o, M);

    attn_mfma<<<dim3(Bc * NH), dim3(NT), 0, stream>>>(
        xqb, xkb, xvb, r_o, v_tab_x, v_tab_y, x_dist, y_dist, aob);

    mfma_gemm1<<<dim3((M + 127) / 128, 6), dim3(256), 0, stream>>>(
        aob, wob, bo, out, M);
}

// Round 15
// 174.740 us; speedup vs baseline: 1.2944x; 1.2944x over previous
//
#include <hip/hip_runtime.h>
#include <math.h>

#define SEQ 197
#define EMB 768
#define NH  12
#define HD  64
#define NE  28
#define SK  208
#define VP  232
#define PP  232
#define EP  232
#define HP  68
#define TP  66
#define NW  7
#define NT  448

typedef __attribute__((ext_vector_type(8))) __bf16 bf16x8;
typedef __attribute__((ext_vector_type(4))) float  f32x4;

__device__ __forceinline__ unsigned short f2bf(float f) {
    unsigned u = __float_as_uint(f);
    u += 0x7fffu + ((u >> 16) & 1u);
    return (unsigned short)(u >> 16);
}
__device__ __forceinline__ float bfl(unsigned u) { return __uint_as_float(u << 16); }

__device__ __forceinline__ void gl_lds16(const ushort* g, ushort* l) {
    __builtin_amdgcn_global_load_lds(
        (const __attribute__((address_space(1))) unsigned int*)g,
        (__attribute__((address_space(3))) unsigned int*)l, 16, 0, 0);
}

// ---------------------------------------------------------------------------
// prep kernels
// ---------------------------------------------------------------------------
__global__ void cvt_k(const float* __restrict__ src, ushort* __restrict__ dst, int n4) {
    int i = blockIdx.x * 256 + threadIdx.x;
    if (i < n4) {
        float4 v = ((const float4*)src)[i];
        ushort4 o = { f2bf(v.x), f2bf(v.y), f2bf(v.z), f2bf(v.w) };
        ((ushort4*)dst)[i] = o;
    }
}

__global__ void cvt_w4(const float* __restrict__ wq, const float* __restrict__ wk,
                       const float* __restrict__ wv, const float* __restrict__ wo,
                       ushort* __restrict__ wqkv, ushort* __restrict__ wob) {
    int i = blockIdx.x * 256 + threadIdx.x;
    if (i >= 4 * 147456) return;
    int seg = i / 147456, r = i - seg * 147456;
    const float* s = (seg == 0) ? wq : (seg == 1) ? wk : (seg == 2) ? wv : wo;
    float4 v = ((const float4*)s)[r];
    ushort4 o = { f2bf(v.x), f2bf(v.y), f2bf(v.z), f2bf(v.w) };
    if (seg < 3) ((ushort4*)wqkv)[(size_t)seg * 147456 + r] = o;
    else         ((ushort4*)wob)[r] = o;
}

// ---------------------------------------------------------------------------
// rxy via tiny MFMA GEMM: rx[bh][q][e] = sum_{d<64} Q[bh][q][d] * qtab[e][d]
// where qtab[e][d] = qtx[e][d] (e<28, d<32) / qty[e-28][d-32] (28<=e<56,
// d>=32) / 0. Q already includes bq, so no separate bias term. One block
// per (b,h), 4 waves; ~104 MFMAs/block. Replaces the K=768 rel region of
// gemm<0> (25% of its blocks) + wr_prep + rbias_k.
// ---------------------------------------------------------------------------
__global__ __launch_bounds__(256) void rxy_gemm(
    const ushort* __restrict__ xq,
    const float* __restrict__ qtx, const float* __restrict__ qty,
    ushort* __restrict__ r_o)
{
    __shared__ __align__(16) ushort qtab_s[64][66];

    const int bh = blockIdx.x;
    const size_t base = (size_t)bh * SEQ * HD;
    const int tid = threadIdx.x;
    const int w = tid >> 6, lane = tid & 63;
    const int g = lane >> 4, c15 = lane & 15;

    for (int idx = tid; idx < 64 * 64; idx += 256) {
        const int e = idx >> 6, d = idx & 63;
        float v = 0.f;
        if (e < 28)      { if (d < 32)  v = qtx[e * 32 + d]; }
        else if (e < 56) { if (d >= 32) v = qty[(e - 28) * 32 + (d - 32)]; }
        qtab_s[e][d] = f2bf(v);
    }
    __syncthreads();

    for (int qt = w; qt < 13; qt += 4) {
        const int qrow = qt * 16 + c15;
        const int qld = (qrow < SEQ) ? qrow : SEQ - 1;
        const bf16x8 qa0 = *(const bf16x8*)(xq + base + (size_t)qld * HD + g * 8);
        const bf16x8 qa1 = *(const bf16x8*)(xq + base + (size_t)qld * HD + 32 + g * 8);
#pragma unroll
        for (int et = 0; et < 4; et++) {
            bf16x8 t0 = *(const bf16x8*)&qtab_s[et * 16 + c15][g * 8];
            bf16x8 t1 = *(const bf16x8*)&qtab_s[et * 16 + c15][32 + g * 8];
            f32x4 a = (f32x4)0.f;
            a = __builtin_amdgcn_mfma_f32_16x16x32_bf16(qa0, t0, a, 0, 0, 0);
            a = __builtin_amdgcn_mfma_f32_16x16x32_bf16(qa1, t1, a, 0, 0, 0);
#pragma unroll
            for (int r = 0; r < 4; r++) {
                const int q = qt * 16 + g * 4 + r;
                const int e = et * 16 + c15;
                if (q < SEQ && e < 56)
                    r_o[((size_t)bh * SEQ + q) * 56 + e] = f2bf(a[r]);
            }
        }
    }
}

// ---------------------------------------------------------------------------
// 128x128 m97-pattern GEMM, XCD-chunked swizzle (r13). MODE 0: qkv scatter
// only (rel region moved to rxy_gemm, grid.y = 18). MODE 1: out proj fp32.
// ---------------------------------------------------------------------------
__global__ __launch_bounds__(256, 2) void gemm0(
    const ushort* __restrict__ A, const ushort* __restrict__ W,
    const float* __restrict__ b0, const float* __restrict__ b1, const float* __restrict__ b2,
    ushort* __restrict__ q_o, ushort* __restrict__ k_o, ushort* __restrict__ v_o, int M)
{
    __shared__ __align__(16) ushort As[128 * 32];
    __shared__ __align__(16) ushort Bs[128 * 32];

    const int tid  = threadIdx.x;
    const int w    = tid >> 6, lane = tid & 63;
    const int wr   = w >> 1,  wc   = w & 1;

    const int nmt = gridDim.x, nnt = gridDim.y;
    const int lin = blockIdx.y * nmt + blockIdx.x;
    const int gsz = 8 * nnt;
    const int grp = lin / gsz;
    const int rr  = lin - grp * gsz;
    int mig = nmt - grp * 8; if (mig > 8) mig = 8;
    const int mt  = grp * 8 + rr % mig;
    const int nt  = rr / mig;
    const int m0  = mt * 128;
    const int n0  = nt * 128;

    const int srow = tid >> 2;
    const int skb  = (tid & 3) * 8;

    f32x4 acc[4][4];
#pragma unroll
    for (int m = 0; m < 4; m++)
#pragma unroll
        for (int n = 0; n < 4; n++) acc[m][n] = (f32x4)0.f;

    int ra0 = m0 + srow;       if (ra0 >= M) ra0 = M - 1;
    int ra1 = m0 + 64 + srow;  if (ra1 >= M) ra1 = M - 1;
    const int rb0 = n0 + srow, rb1 = n0 + 64 + srow;

    for (int k0 = 0; k0 < EMB; k0 += 32) {
        gl_lds16(A + (size_t)ra0 * EMB + k0 + skb, As + (w * 512));
        gl_lds16(A + (size_t)ra1 * EMB + k0 + skb, As + (2048 + w * 512));
        gl_lds16(W + (size_t)rb0 * EMB + k0 + skb, Bs + (w * 512));
        gl_lds16(W + (size_t)rb1 * EMB + k0 + skb, Bs + (2048 + w * 512));
        __syncthreads();

        bf16x8 af[4], bfr[4];
#pragma unroll
        for (int m = 0; m < 4; m++)
            af[m] = *(const bf16x8*)&As[(wr * 64 + m * 16 + (lane & 15)) * 32 + (lane >> 4) * 8];
#pragma unroll
        for (int n = 0; n < 4; n++)
            bfr[n] = *(const bf16x8*)&Bs[(wc * 64 + n * 16 + (lane & 15)) * 32 + (lane >> 4) * 8];
#pragma unroll
        for (int m = 0; m < 4; m++)
#pragma unroll
            for (int n = 0; n < 4; n++)
                acc[m][n] = __builtin_amdgcn_mfma_f32_16x16x32_bf16(af[m], bfr[n], acc[m][n], 0, 0, 0);
        __syncthreads();
    }

    const int mat = n0 / EMB;
    const int nr  = n0 - mat * EMB;
    const float* bias = (mat == 0) ? b0 : (mat == 1) ? b1 : b2;
    ushort* dst = (mat == 0) ? q_o : (mat == 1) ? k_o : v_o;

#pragma unroll
    for (int m = 0; m < 4; m++) {
#pragma unroll
        for (int r = 0; r < 4; r++) {
            const int gm = m0 + wr * 64 + m * 16 + (lane >> 4) * 4 + r;
            if (gm >= M) continue;
            const int bb = gm / SEQ, ss = gm - bb * SEQ;
#pragma unroll
            for (int n = 0; n < 4; n++) {
                const int col = nr + wc * 64 + n * 16 + (lane & 15);
                const float v = acc[m][n][r] + bias[col];
                dst[(((size_t)bb * NH + (col >> 6)) * SEQ + ss) * HD + (col & 63)] = f2bf(v);
            }
        }
    }
}

__global__ __launch_bounds__(256, 2) void gemm1(
    const ushort* __restrict__ A, const ushort* __restrict__ W,
    const float* __restrict__ b0, float* __restrict__ f_o, int M)
{
    __shared__ __align__(16) ushort As[128 * 32];
    __shared__ __align__(16) ushort Bs[128 * 32];

    const int tid  = threadIdx.x;
    const int w    = tid >> 6, lane = tid & 63;
    const int wr   = w >> 1,  wc   = w & 1;

    const int nmt = gridDim.x, nnt = gridDim.y;
    const int lin = blockIdx.y * nmt + blockIdx.x;
    const int gsz = 8 * nnt;
    const int grp = lin / gsz;
    const int rr  = lin - grp * gsz;
    int mig = nmt - grp * 8; if (mig > 8) mig = 8;
    const int mt  = grp * 8 + rr % mig;
    const int nt  = rr / mig;
    const int m0  = mt * 128;
    const int n0  = nt * 128;

    const int srow = tid >> 2;
    const int skb  = (tid & 3) * 8;

    f32x4 acc[4][4];
#pragma unroll
    for (int m = 0; m < 4; m++)
#pragma unroll
        for (int n = 0; n < 4; n++) acc[m][n] = (f32x4)0.f;

    int ra0 = m0 + srow;       if (ra0 >= M) ra0 = M - 1;
    int ra1 = m0 + 64 + srow;  if (ra1 >= M) ra1 = M - 1;
    const int rb0 = n0 + srow, rb1 = n0 + 64 + srow;

    for (int k0 = 0; k0 < EMB; k0 += 32) {
        gl_lds16(A + (size_t)ra0 * EMB + k0 + skb, As + (w * 512));
        gl_lds16(A + (size_t)ra1 * EMB + k0 + skb, As + (2048 + w * 512));
        gl_lds16(W + (size_t)rb0 * EMB + k0 + skb, Bs + (w * 512));
        gl_lds16(W + (size_t)rb1 * EMB + k0 + skb, Bs + (2048 + w * 512));
        __syncthreads();

        bf16x8 af[4], bfr[4];
#pragma unroll
        for (int m = 0; m < 4; m++)
            af[m] = *(const bf16x8*)&As[(wr * 64 + m * 16 + (lane & 15)) * 32 + (lane >> 4) * 8];
#pragma unroll
        for (int n = 0; n < 4; n++)
            bfr[n] = *(const bf16x8*)&Bs[(wc * 64 + n * 16 + (lane & 15)) * 32 + (lane >> 4) * 8];
#pragma unroll
        for (int m = 0; m < 4; m++)
#pragma unroll
            for (int n = 0; n < 4; n++)
                acc[m][n] = __builtin_amdgcn_mfma_f32_16x16x32_bf16(af[m], bfr[n], acc[m][n], 0, 0, 0);
        __syncthreads();
    }

#pragma unroll
    for (int m = 0; m < 4; m++) {
#pragma unroll
        for (int r = 0; r < 4; r++) {
            const int gm = m0 + wr * 64 + m * 16 + (lane >> 4) * 4 + r;
            if (gm >= M) continue;
#pragma unroll
            for (int n = 0; n < 4; n++) {
                const int col = n0 + wc * 64 + n * 16 + (lane & 15);
                f_o[(size_t)gm * EMB + col] = acc[m][n][r] + b0[col];
            }
        }
    }
}

// ---------------------------------------------------------------------------
// MFMA fused attention (r12 one-hot factorization) — unchanged.
// ---------------------------------------------------------------------------
__global__ __launch_bounds__(NT) void attn_mfma(
    const ushort* __restrict__ xq, const ushort* __restrict__ xk, const ushort* __restrict__ xv,
    const ushort* __restrict__ rxy_g,
    const float* __restrict__ v_tab_x, const float* __restrict__ v_tab_y,
    const int* __restrict__ x_dist, const int* __restrict__ y_dist,
    ushort* __restrict__ ao)
{
    __shared__ __align__(16) ushort K_s[SK * HD];
    __shared__ __align__(16) ushort EXYs_s[SK * 40];
    __shared__ __align__(16) ushort EXYT_s[32 * EP];
    __shared__ __align__(16) ushort VT_s[HD * VP];
    __shared__ __align__(16) ushort P_s[NW * 16 * PP];
    __shared__ __align__(16) ushort vt_s[HD * TP];
    __shared__ __align__(16) ushort h_s[NW][16][HP];

    const int bh = blockIdx.x;
    const int b  = bh / NH;
    const int h  = bh % NH;
    const size_t base = (size_t)bh * SEQ * HD;
    const ushort* __restrict__ rxy_b = rxy_g + (size_t)bh * SEQ * 56;
    const int tid = threadIdx.x;
    const int w = tid >> 6, lane = tid & 63;
    const int g = lane >> 4, c15 = lane & 15;

    for (int idx = tid; idx < SK * 8; idx += NT) {
        const int r = idx >> 3, c = idx & 7;
        uint4 v = make_uint4(0, 0, 0, 0);
        if (r < SEQ) v = *(const uint4*)(xk + base + r * HD + c * 8);
        *(uint4*)&K_s[r * HD + ((c ^ (r & 7)) << 3)] = v;
    }
    for (int idx = tid; idx < SK * 40 / 8; idx += NT)
        *(uint4*)&EXYs_s[idx * 8] = make_uint4(0, 0, 0, 0);
    for (int idx = tid; idx < 32 * EP / 8; idx += NT)
        *(uint4*)&EXYT_s[idx * 8] = make_uint4(0, 0, 0, 0);
    for (int idx = tid; idx < HD * (VP - SEQ); idx += NT) {
        const int d = idx / (VP - SEQ), k = SEQ + idx - d * (VP - SEQ);
        VT_s[d * VP + k] = 0;
    }
    for (int idx = tid; idx < NW * 16 * PP / 8; idx += NT)
        *(uint4*)&P_s[idx * 8] = make_uint4(0, 0, 0, 0);
    for (int idx = tid; idx < 16 * 8 * 13; idx += NT) {
        const int kq = idx & 15, t = idx >> 4;
        const int db = t & 7, kh = t >> 3;
        const int k = kh * 16 + kq;
        if (k >= SEQ) continue;
        uint4 v = *(const uint4*)(xv + base + k * HD + db * 8);
        ushort* col = &VT_s[(db * 8) * VP + k];
        col[0 * VP] = (ushort)(v.x); col[1 * VP] = (ushort)(v.x >> 16);
        col[2 * VP] = (ushort)(v.y); col[3 * VP] = (ushort)(v.y >> 16);
        col[4 * VP] = (ushort)(v.z); col[5 * VP] = (ushort)(v.z >> 16);
        col[6 * VP] = (ushort)(v.w); col[7 * VP] = (ushort)(v.w >> 16);
    }
    for (int idx = tid; idx < HD * 64; idx += NT) {
        const int d = idx >> 6, e = idx & 63;
        float v = 0.f;
        if (d < 32) { if (e < 28) v = v_tab_x[e * 32 + d]; }
        else        { if (e >= 28 && e < 56) v = v_tab_y[(e - 28) * 32 + (d - 32)]; }
        vt_s[d * TP + e] = f2bf(v);
    }
    __syncthreads();
    for (int k = tid; k < SEQ; k += NT) {
        const int cx = (k == 0) ? 14 : (x_dist[SEQ + k] - 14);
        const int cy = (k == 0) ? 14 : (y_dist[SEQ + k] - 14);
        const ushort one = 0x3f80;
        EXYs_s[k * 40 + cx]        = one;
        EXYs_s[k * 40 + 16 + cy]   = one;
        EXYT_s[cx * EP + k]        = one;
        EXYT_s[(16 + cy) * EP + k] = one;
    }
    __syncthreads();

    for (int qt = w; qt < 13; qt += NW) {
        const int qrow = qt * 16 + c15;
        const int qld  = (qrow < SEQ) ? qrow : (SEQ - 1);
        const bf16x8 qa0 = *(const bf16x8*)(xq + base + (size_t)qld * HD + g * 8);
        const bf16x8 qa1 = *(const bf16x8*)(xq + base + (size_t)qld * HD + 32 + g * 8);

        uint4 up;
        {
            const ushort* rrow = rxy_b + qld * 56;
            const int cxq = (qld > 0) ? (x_dist[SEQ + qld] - 14) : 0;
            const int cyq = (qld > 0) ? (y_dist[SEQ + qld] - 14) : 0;
            unsigned uu[4] = {0, 0, 0, 0};
#pragma unroll
            for (int j = 0; j < 8; j++) {
                const int c = g * 8 + j;
                ushort v;
                if (qld == 0)      v = (c == 15 || c == 31) ? (ushort)0 : rrow[(c < 16) ? 0 : 28];
                else if (c < 14)   v = rrow[c - cxq + 14];
                else if (c == 14)  v = rrow[0];
                else if (c == 15)  v = 0;
                else if (c < 30)   v = rrow[28 + (c - 16) - cyq + 14];
                else if (c == 30)  v = rrow[28];
                else               v = 0;
                uu[j >> 1] |= ((unsigned)v) << ((j & 1) * 16);
            }
            up.x = uu[0]; up.y = uu[1]; up.z = uu[2]; up.w = uu[3];
        }
        const bf16x8 qa2 = *(bf16x8*)&up;

        {
            uint4* hz = (uint4*)h_s[w];
            for (int i = lane; i < 16 * HP / 8; i += 64) hz[i] = make_uint4(0, 0, 0, 0);
        }

        const int q4 = qt * 16 + 4 * g;
        float sum[4] = {0.f, 0.f, 0.f, 0.f};

#pragma unroll
        for (int kt = 0; kt < 13; kt++) {
            const int kr = kt * 16 + c15;
            bf16x8 kf0 = *(const bf16x8*)&K_s[kr * HD + (((0 + g) ^ (kr & 7)) << 3)];
            bf16x8 kf1 = *(const bf16x8*)&K_s[kr * HD + (((4 + g) ^ (kr & 7)) << 3)];
            bf16x8 kf2 = *(const bf16x8*)&EXYs_s[kr * 40 + g * 8];
            f32x4 a = (f32x4)0.f;
            a = __builtin_amdgcn_mfma_f32_16x16x32_bf16(qa0, kf0, a, 0, 0, 0);
            a = __builtin_amdgcn_mfma_f32_16x16x32_bf16(qa1, kf1, a, 0, 0, 0);
            a = __builtin_amdgcn_mfma_f32_16x16x32_bf16(qa2, kf2, a, 0, 0, 0);
#pragma unroll
            for (int r = 0; r < 4; r++) {
                const float l = a[r] * 0.125f - 8.0f;
                const float p = (kr < SEQ) ? __expf(l) : 0.f;
                sum[r] += p;
                P_s[(w * 16 + 4 * g + r) * PP + kr] = f2bf(p);
            }
        }
        float inv[4];
#pragma unroll
        for (int r = 0; r < 4; r++) {
            sum[r] += __shfl_xor(sum[r], 1);
            sum[r] += __shfl_xor(sum[r], 2);
            sum[r] += __shfl_xor(sum[r], 4);
            sum[r] += __shfl_xor(sum[r], 8);
            inv[r] = 1.f / sum[r];
        }

        f32x4 px0 = (f32x4)0.f, px1 = (f32x4)0.f;
#pragma unroll
        for (int ks = 0; ks < 7; ks++) {
            bf16x8 pf = *(const bf16x8*)&P_s[(w * 16 + c15) * PP + ks * 32 + g * 8];
            bf16x8 e0 = *(const bf16x8*)&EXYT_s[c15 * EP + ks * 32 + g * 8];
            bf16x8 e1 = *(const bf16x8*)&EXYT_s[(16 + c15) * EP + ks * 32 + g * 8];
            px0 = __builtin_amdgcn_mfma_f32_16x16x32_bf16(pf, e0, px0, 0, 0, 0);
            px1 = __builtin_amdgcn_mfma_f32_16x16x32_bf16(pf, e1, px1, 0, 0, 0);
        }

        float sx = px0[0], sy = px1[0];
        if (qt == 0) {
            sx += __shfl_xor(sx, 1); sx += __shfl_xor(sx, 2);
            sx += __shfl_xor(sx, 4); sx += __shfl_xor(sx, 8);
            sy += __shfl_xor(sy, 1); sy += __shfl_xor(sy, 2);
            sy += __shfl_xor(sy, 4); sy += __shfl_xor(sy, 8);
        }

#pragma unroll
        for (int r = 0; r < 4; r++) {
            const int q = q4 + r;
            if (q >= SEQ) continue;
            const int ql = 4 * g + r;
            if (q == 0) {
                if (c15 == 14) { h_s[w][ql][0] = f2bf(sx); h_s[w][ql][28] = f2bf(sy); }
            } else {
                const int cxq2 = x_dist[SEQ + q] - 14;
                const int cyq2 = y_dist[SEQ + q] - 14;
                if (c15 < 14) {
                    h_s[w][ql][c15 - cxq2 + 14]      = f2bf(px0[r]);
                    h_s[w][ql][28 + c15 - cyq2 + 14] = f2bf(px1[r]);
                } else if (c15 == 14) {
                    h_s[w][ql][0]  = f2bf(px0[r]);
                    h_s[w][ql][28] = f2bf(px1[r]);
                }
            }
        }

        f32x4 o[4];
#pragma unroll
        for (int dt = 0; dt < 4; dt++) o[dt] = (f32x4)0.f;
#pragma unroll
        for (int ks = 0; ks < 7; ks++) {
            bf16x8 pf = *(const bf16x8*)&P_s[(w * 16 + c15) * PP + ks * 32 + g * 8];
#pragma unroll
            for (int dt = 0; dt < 4; dt++) {
                bf16x8 vf = *(const bf16x8*)&VT_s[(dt * 16 + c15) * VP + ks * 32 + g * 8];
                o[dt] = __builtin_amdgcn_mfma_f32_16x16x32_bf16(pf, vf, o[dt], 0, 0, 0);
            }
        }
#pragma unroll
        for (int ks2 = 0; ks2 < 2; ks2++) {
            bf16x8 hf = *(const bf16x8*)&h_s[w][c15][ks2 * 32 + g * 8];
#pragma unroll
            for (int dt = 0; dt < 4; dt++) {
                bf16x8 tf = *(const bf16x8*)&vt_s[(dt * 16 + c15) * TP + ks2 * 32 + g * 8];
                o[dt] = __builtin_amdgcn_mfma_f32_16x16x32_bf16(hf, tf, o[dt], 0, 0, 0);
            }
        }

#pragma unroll
        for (int dt = 0; dt < 4; dt++) {
            const int d = dt * 16 + c15;
#pragma unroll
            for (int r = 0; r < 4; r++) {
                const int q = q4 + r;
                if (q < SEQ)
                    ao[((size_t)(b * SEQ + q)) * EMB + h * HD + d] = f2bf(o[dt][r] * inv[r]);
            }
        }
    }
}

extern "C" void kernel_launch(void* const* d_in, const int* in_sizes, int n_in,
                              void* d_out, int out_size, void* d_ws, size_t ws_size,
                              hipStream_t stream) {
    const float* x       = (const float*)d_in[0];
    const float* Wq      = (const float*)d_in[1];
    const float* bq      = (const float*)d_in[2];
    const float* Wk      = (const float*)d_in[3];
    const float* bk      = (const float*)d_in[4];
    const float* Wv      = (const float*)d_in[5];
    const float* bv      = (const float*)d_in[6];
    const float* Wo      = (const float*)d_in[7];
    const float* bo      = (const float*)d_in[8];
    const float* q_tab_x = (const float*)d_in[9];
    const float* q_tab_y = (const float*)d_in[10];
    const float* v_tab_x = (const float*)d_in[11];
    const float* v_tab_y = (const float*)d_in[12];
    const int*   x_dist  = (const int*)d_in[13];
    const int*   y_dist  = (const int*)d_in[14];
    float* out = (float*)d_out;

    const int M  = in_sizes[0] / EMB;   // 12608
    const int Bc = M / SEQ;             // 64

    ushort* xb   = (ushort*)d_ws;
    ushort* wqkv = xb   + (size_t)M * EMB;              // 2304*768
    ushort* wob  = wqkv + (size_t)2304 * EMB;           // 768*768
    ushort* xqb  = wob  + (size_t)EMB * EMB;
    ushort* xkb  = xqb  + (size_t)M * EMB;
    ushort* xvb  = xkb  + (size_t)M * EMB;
    ushort* aob  = xvb  + (size_t)M * EMB;
    ushort* r_o  = aob  + (size_t)M * EMB;              // 768*197*56

    const int n4x = M * EMB / 4;
    cvt_k<<<dim3((n4x + 255) / 256), dim3(256), 0, stream>>>(x, xb, n4x);
    cvt_w4<<<dim3(2304), dim3(256), 0, stream>>>(Wq, Wk, Wv, Wo, wqkv, wob);

    gemm0<<<dim3((M + 127) / 128, 18), dim3(256), 0, stream>>>(
        xb, wqkv, bq, bk, bv, xqb, xkb, xvb, M);

    rxy_gemm<<<dim3(Bc * NH), dim3(256), 0, stream>>>(xqb, q_tab_x, q_tab_y, r_o);

    attn_mfma<<<dim3(Bc * NH), dim3(NT), 0, stream>>>(
        xqb, xkb, xvb, r_o, v_tab_x, v_tab_y, x_dist, y_dist, aob);

    gemm1<<<dim3((M + 127) / 128, 6), dim3(256), 0, stream>>>(
        aob, wob, bo, out, M);
}

// Round 16
// 161.035 us; speedup vs baseline: 1.4046x; 1.0851x over previous
//
#include <hip/hip_runtime.h>
#include <math.h>

#define SEQ 197
#define EMB 768
#define NH  12
#define HD  64
#define NE  28
#define SK  208
#define VP  232
#define PP  232
#define EP  232
#define HP  68
#define TP  66
#define NW  7
#define NT  448

typedef __attribute__((ext_vector_type(8))) __bf16 bf16x8;
typedef __attribute__((ext_vector_type(4))) float  f32x4;

__device__ __forceinline__ unsigned short f2bf(float f) {
    unsigned u = __float_as_uint(f);
    u += 0x7fffu + ((u >> 16) & 1u);
    return (unsigned short)(u >> 16);
}
__device__ __forceinline__ float bfl(unsigned u) { return __uint_as_float(u << 16); }

__device__ __forceinline__ void gl_lds16(const ushort* g, ushort* l) {
    __builtin_amdgcn_global_load_lds(
        (const __attribute__((address_space(1))) unsigned int*)g,
        (__attribute__((address_space(3))) unsigned int*)l, 16, 0, 0);
}

// ---------------------------------------------------------------------------
// prep kernels
// ---------------------------------------------------------------------------
__global__ void cvt_k(const float* __restrict__ src, ushort* __restrict__ dst, int n4) {
    int i = blockIdx.x * 256 + threadIdx.x;
    if (i < n4) {
        float4 v = ((const float4*)src)[i];
        ushort4 o = { f2bf(v.x), f2bf(v.y), f2bf(v.z), f2bf(v.w) };
        ((ushort4*)dst)[i] = o;
    }
}

__global__ void cvt_w4(const float* __restrict__ wq, const float* __restrict__ wk,
                       const float* __restrict__ wv, const float* __restrict__ wo,
                       ushort* __restrict__ wqkv, ushort* __restrict__ wob) {
    int i = blockIdx.x * 256 + threadIdx.x;
    if (i >= 4 * 147456) return;
    int seg = i / 147456, r = i - seg * 147456;
    const float* s = (seg == 0) ? wq : (seg == 1) ? wk : (seg == 2) ? wv : wo;
    float4 v = ((const float4*)s)[r];
    ushort4 o = { f2bf(v.x), f2bf(v.y), f2bf(v.z), f2bf(v.w) };
    if (seg < 3) ((ushort4*)wqkv)[(size_t)seg * 147456 + r] = o;
    else         ((ushort4*)wob)[r] = o;
}

// ---------------------------------------------------------------------------
// rxy via tiny MFMA GEMM (r15) — unchanged.
// ---------------------------------------------------------------------------
__global__ __launch_bounds__(256) void rxy_gemm(
    const ushort* __restrict__ xq,
    const float* __restrict__ qtx, const float* __restrict__ qty,
    ushort* __restrict__ r_o)
{
    __shared__ __align__(16) ushort qtab_s[64][66];

    const int bh = blockIdx.x;
    const size_t base = (size_t)bh * SEQ * HD;
    const int tid = threadIdx.x;
    const int w = tid >> 6, lane = tid & 63;
    const int g = lane >> 4, c15 = lane & 15;

    for (int idx = tid; idx < 64 * 64; idx += 256) {
        const int e = idx >> 6, d = idx & 63;
        float v = 0.f;
        if (e < 28)      { if (d < 32)  v = qtx[e * 32 + d]; }
        else if (e < 56) { if (d >= 32) v = qty[(e - 28) * 32 + (d - 32)]; }
        qtab_s[e][d] = f2bf(v);
    }
    __syncthreads();

    for (int qt = w; qt < 13; qt += 4) {
        const int qrow = qt * 16 + c15;
        const int qld = (qrow < SEQ) ? qrow : SEQ - 1;
        const bf16x8 qa0 = *(const bf16x8*)(xq + base + (size_t)qld * HD + g * 8);
        const bf16x8 qa1 = *(const bf16x8*)(xq + base + (size_t)qld * HD + 32 + g * 8);
#pragma unroll
        for (int et = 0; et < 4; et++) {
            bf16x8 t0 = *(const bf16x8*)&qtab_s[et * 16 + c15][g * 8];
            bf16x8 t1 = *(const bf16x8*)&qtab_s[et * 16 + c15][32 + g * 8];
            f32x4 a = (f32x4)0.f;
            a = __builtin_amdgcn_mfma_f32_16x16x32_bf16(qa0, t0, a, 0, 0, 0);
            a = __builtin_amdgcn_mfma_f32_16x16x32_bf16(qa1, t1, a, 0, 0, 0);
#pragma unroll
            for (int r = 0; r < 4; r++) {
                const int q = qt * 16 + g * 4 + r;
                const int e = et * 16 + c15;
                if (q < SEQ && e < 56)
                    r_o[((size_t)bh * SEQ + q) * 56 + e] = f2bf(a[r]);
            }
        }
    }
}

// ---------------------------------------------------------------------------
// 128x128 GEMM, BK=64 (r16): 12 sync rounds instead of 24 — doubles the
// MFMA work amortizing each barrier drain. 128B LDS rows would be a 16-way
// bank conflict, so both tiles use the attn-K_s pattern (verified r8+):
// linear gl_lds dest + source chunk ^(row&7) + read offset ^(row&7).
// XCD-chunked swizzle retained. MODE 0: qkv scatter; MODE 1: fp32 out.
// ---------------------------------------------------------------------------
template<int MODE>
__global__ __launch_bounds__(256, 2) void gemm_k64(
    const ushort* __restrict__ A, const ushort* __restrict__ W,
    const float* __restrict__ b0, const float* __restrict__ b1, const float* __restrict__ b2,
    ushort* __restrict__ q_o, ushort* __restrict__ k_o, ushort* __restrict__ v_o,
    float* __restrict__ f_o, int M)
{
    __shared__ __align__(16) ushort As[128 * 64];   // 16 KB, row = 128 B
    __shared__ __align__(16) ushort Bs[128 * 64];   // 16 KB

    const int tid  = threadIdx.x;
    const int w    = tid >> 6, lane = tid & 63;
    const int wr   = w >> 1,  wc   = w & 1;

    const int nmt = gridDim.x, nnt = gridDim.y;
    const int lin = blockIdx.y * nmt + blockIdx.x;
    const int gsz = 8 * nnt;
    const int grp = lin / gsz;
    const int rr  = lin - grp * gsz;
    int mig = nmt - grp * 8; if (mig > 8) mig = 8;
    const int mt  = grp * 8 + rr % mig;
    const int nt  = rr / mig;
    const int m0  = mt * 128;
    const int n0  = nt * 128;

    // staging granule map: g = tid + i*256 ; row = g>>3, chunk = g&7 (16B)
    int arow[4], asrc[4];
#pragma unroll
    for (int i = 0; i < 4; i++) {
        const int gidx = tid + i * 256;
        const int row = gidx >> 3, ch = gidx & 7;
        arow[i] = row;
        asrc[i] = (ch ^ (row & 7)) * 8;   // ushort offset within the 64-elem row
    }

    f32x4 acc[4][4];
#pragma unroll
    for (int m = 0; m < 4; m++)
#pragma unroll
        for (int n = 0; n < 4; n++) acc[m][n] = (f32x4)0.f;

    for (int k0 = 0; k0 < EMB; k0 += 64) {
#pragma unroll
        for (int i = 0; i < 4; i++) {
            int ra = m0 + arow[i]; if (ra >= M) ra = M - 1;
            gl_lds16(A + (size_t)ra * EMB + k0 + asrc[i], As + (tid + i * 256) * 8);
            gl_lds16(W + (size_t)(n0 + arow[i]) * EMB + k0 + asrc[i], Bs + (tid + i * 256) * 8);
        }
        __syncthreads();

#pragma unroll
        for (int kk = 0; kk < 2; kk++) {
            bf16x8 af[4], bfr[4];
#pragma unroll
            for (int m = 0; m < 4; m++) {
                const int row = wr * 64 + m * 16 + (lane & 15);
                af[m] = *(const bf16x8*)&As[row * 64 + (((kk * 4 + (lane >> 4)) ^ (row & 7)) << 3)];
            }
#pragma unroll
            for (int n = 0; n < 4; n++) {
                const int row = wc * 64 + n * 16 + (lane & 15);
                bfr[n] = *(const bf16x8*)&Bs[row * 64 + (((kk * 4 + (lane >> 4)) ^ (row & 7)) << 3)];
            }
#pragma unroll
            for (int m = 0; m < 4; m++)
#pragma unroll
                for (int n = 0; n < 4; n++)
                    acc[m][n] = __builtin_amdgcn_mfma_f32_16x16x32_bf16(af[m], bfr[n], acc[m][n], 0, 0, 0);
        }
        __syncthreads();
    }

    const int mat = n0 / EMB;
    const int nr  = n0 - mat * EMB;
    const float* bias = (mat == 0) ? b0 : (mat == 1) ? b1 : b2;
    ushort* dst = (mat == 0) ? q_o : (mat == 1) ? k_o : v_o;

#pragma unroll
    for (int m = 0; m < 4; m++) {
#pragma unroll
        for (int r = 0; r < 4; r++) {
            const int gm = m0 + wr * 64 + m * 16 + (lane >> 4) * 4 + r;
            if (gm >= M) continue;
            const int bb = gm / SEQ, ss = gm - bb * SEQ;
#pragma unroll
            for (int n = 0; n < 4; n++) {
                const int col = nr + wc * 64 + n * 16 + (lane & 15);
                if (MODE == 0) {
                    const float v = acc[m][n][r] + bias[col];
                    dst[(((size_t)bb * NH + (col >> 6)) * SEQ + ss) * HD + (col & 63)] = f2bf(v);
                } else {
                    f_o[(size_t)gm * EMB + col] = acc[m][n][r] + b0[col];
                }
            }
        }
    }
}

// ---------------------------------------------------------------------------
// MFMA fused attention (r12 one-hot factorization) — unchanged.
// ---------------------------------------------------------------------------
__global__ __launch_bounds__(NT) void attn_mfma(
    const ushort* __restrict__ xq, const ushort* __restrict__ xk, const ushort* __restrict__ xv,
    const ushort* __restrict__ rxy_g,
    const float* __restrict__ v_tab_x, const float* __restrict__ v_tab_y,
    const int* __restrict__ x_dist, const int* __restrict__ y_dist,
    ushort* __restrict__ ao)
{
    __shared__ __align__(16) ushort K_s[SK * HD];
    __shared__ __align__(16) ushort EXYs_s[SK * 40];
    __shared__ __align__(16) ushort EXYT_s[32 * EP];
    __shared__ __align__(16) ushort VT_s[HD * VP];
    __shared__ __align__(16) ushort P_s[NW * 16 * PP];
    __shared__ __align__(16) ushort vt_s[HD * TP];
    __shared__ __align__(16) ushort h_s[NW][16][HP];

    const int bh = blockIdx.x;
    const int b  = bh / NH;
    const int h  = bh % NH;
    const size_t base = (size_t)bh * SEQ * HD;
    const ushort* __restrict__ rxy_b = rxy_g + (size_t)bh * SEQ * 56;
    const int tid = threadIdx.x;
    const int w = tid >> 6, lane = tid & 63;
    const int g = lane >> 4, c15 = lane & 15;

    for (int idx = tid; idx < SK * 8; idx += NT) {
        const int r = idx >> 3, c = idx & 7;
        uint4 v = make_uint4(0, 0, 0, 0);
        if (r < SEQ) v = *(const uint4*)(xk + base + r * HD + c * 8);
        *(uint4*)&K_s[r * HD + ((c ^ (r & 7)) << 3)] = v;
    }
    for (int idx = tid; idx < SK * 40 / 8; idx += NT)
        *(uint4*)&EXYs_s[idx * 8] = make_uint4(0, 0, 0, 0);
    for (int idx = tid; idx < 32 * EP / 8; idx += NT)
        *(uint4*)&EXYT_s[idx * 8] = make_uint4(0, 0, 0, 0);
    for (int idx = tid; idx < HD * (VP - SEQ); idx += NT) {
        const int d = idx / (VP - SEQ), k = SEQ + idx - d * (VP - SEQ);
        VT_s[d * VP + k] = 0;
    }
    for (int idx = tid; idx < NW * 16 * PP / 8; idx += NT)
        *(uint4*)&P_s[idx * 8] = make_uint4(0, 0, 0, 0);
    for (int idx = tid; idx < 16 * 8 * 13; idx += NT) {
        const int kq = idx & 15, t = idx >> 4;
        const int db = t & 7, kh = t >> 3;
        const int k = kh * 16 + kq;
        if (k >= SEQ) continue;
        uint4 v = *(const uint4*)(xv + base + k * HD + db * 8);
        ushort* col = &VT_s[(db * 8) * VP + k];
        col[0 * VP] = (ushort)(v.x); col[1 * VP] = (ushort)(v.x >> 16);
        col[2 * VP] = (ushort)(v.y); col[3 * VP] = (ushort)(v.y >> 16);
        col[4 * VP] = (ushort)(v.z); col[5 * VP] = (ushort)(v.z >> 16);
        col[6 * VP] = (ushort)(v.w); col[7 * VP] = (ushort)(v.w >> 16);
    }
    for (int idx = tid; idx < HD * 64; idx += NT) {
        const int d = idx >> 6, e = idx & 63;
        float v = 0.f;
        if (d < 32) { if (e < 28) v = v_tab_x[e * 32 + d]; }
        else        { if (e >= 28 && e < 56) v = v_tab_y[(e - 28) * 32 + (d - 32)]; }
        vt_s[d * TP + e] = f2bf(v);
    }
    __syncthreads();
    for (int k = tid; k < SEQ; k += NT) {
        const int cx = (k == 0) ? 14 : (x_dist[SEQ + k] - 14);
        const int cy = (k == 0) ? 14 : (y_dist[SEQ + k] - 14);
        const ushort one = 0x3f80;
        EXYs_s[k * 40 + cx]        = one;
        EXYs_s[k * 40 + 16 + cy]   = one;
        EXYT_s[cx * EP + k]        = one;
        EXYT_s[(16 + cy) * EP + k] = one;
    }
    __syncthreads();

    for (int qt = w; qt < 13; qt += NW) {
        const int qrow = qt * 16 + c15;
        const int qld  = (qrow < SEQ) ? qrow : (SEQ - 1);
        const bf16x8 qa0 = *(const bf16x8*)(xq + base + (size_t)qld * HD + g * 8);
        const bf16x8 qa1 = *(const bf16x8*)(xq + base + (size_t)qld * HD + 32 + g * 8);

        uint4 up;
        {
            const ushort* rrow = rxy_b + qld * 56;
            const int cxq = (qld > 0) ? (x_dist[SEQ + qld] - 14) : 0;
            const int cyq = (qld > 0) ? (y_dist[SEQ + qld] - 14) : 0;
            unsigned uu[4] = {0, 0, 0, 0};
#pragma unroll
            for (int j = 0; j < 8; j++) {
                const int c = g * 8 + j;
                ushort v;
                if (qld == 0)      v = (c == 15 || c == 31) ? (ushort)0 : rrow[(c < 16) ? 0 : 28];
                else if (c < 14)   v = rrow[c - cxq + 14];
                else if (c == 14)  v = rrow[0];
                else if (c == 15)  v = 0;
                else if (c < 30)   v = rrow[28 + (c - 16) - cyq + 14];
                else if (c == 30)  v = rrow[28];
                else               v = 0;
                uu[j >> 1] |= ((unsigned)v) << ((j & 1) * 16);
            }
            up.x = uu[0]; up.y = uu[1]; up.z = uu[2]; up.w = uu[3];
        }
        const bf16x8 qa2 = *(bf16x8*)&up;

        {
            uint4* hz = (uint4*)h_s[w];
            for (int i = lane; i < 16 * HP / 8; i += 64) hz[i] = make_uint4(0, 0, 0, 0);
        }

        const int q4 = qt * 16 + 4 * g;
        float sum[4] = {0.f, 0.f, 0.f, 0.f};

#pragma unroll
        for (int kt = 0; kt < 13; kt++) {
            const int kr = kt * 16 + c15;
            bf16x8 kf0 = *(const bf16x8*)&K_s[kr * HD + (((0 + g) ^ (kr & 7)) << 3)];
            bf16x8 kf1 = *(const bf16x8*)&K_s[kr * HD + (((4 + g) ^ (kr & 7)) << 3)];
            bf16x8 kf2 = *(const bf16x8*)&EXYs_s[kr * 40 + g * 8];
            f32x4 a = (f32x4)0.f;
            a = __builtin_amdgcn_mfma_f32_16x16x32_bf16(qa0, kf0, a, 0, 0, 0);
            a = __builtin_amdgcn_mfma_f32_16x16x32_bf16(qa1, kf1, a, 0, 0, 0);
            a = __builtin_amdgcn_mfma_f32_16x16x32_bf16(qa2, kf2, a, 0, 0, 0);
#pragma unroll
            for (int r = 0; r < 4; r++) {
                const float l = a[r] * 0.125f - 8.0f;
                const float p = (kr < SEQ) ? __expf(l) : 0.f;
                sum[r] += p;
                P_s[(w * 16 + 4 * g + r) * PP + kr] = f2bf(p);
            }
        }
        float inv[4];
#pragma unroll
        for (int r = 0; r < 4; r++) {
            sum[r] += __shfl_xor(sum[r], 1);
            sum[r] += __shfl_xor(sum[r], 2);
            sum[r] += __shfl_xor(sum[r], 4);
            sum[r] += __shfl_xor(sum[r], 8);
            inv[r] = 1.f / sum[r];
        }

        f32x4 px0 = (f32x4)0.f, px1 = (f32x4)0.f;
#pragma unroll
        for (int ks = 0; ks < 7; ks++) {
            bf16x8 pf = *(const bf16x8*)&P_s[(w * 16 + c15) * PP + ks * 32 + g * 8];
            bf16x8 e0 = *(const bf16x8*)&EXYT_s[c15 * EP + ks * 32 + g * 8];
            bf16x8 e1 = *(const bf16x8*)&EXYT_s[(16 + c15) * EP + ks * 32 + g * 8];
            px0 = __builtin_amdgcn_mfma_f32_16x16x32_bf16(pf, e0, px0, 0, 0, 0);
            px1 = __builtin_amdgcn_mfma_f32_16x16x32_bf16(pf, e1, px1, 0, 0, 0);
        }

        float sx = px0[0], sy = px1[0];
        if (qt == 0) {
            sx += __shfl_xor(sx, 1); sx += __shfl_xor(sx, 2);
            sx += __shfl_xor(sx, 4); sx += __shfl_xor(sx, 8);
            sy += __shfl_xor(sy, 1); sy += __shfl_xor(sy, 2);
            sy += __shfl_xor(sy, 4); sy += __shfl_xor(sy, 8);
        }

#pragma unroll
        for (int r = 0; r < 4; r++) {
            const int q = q4 + r;
            if (q >= SEQ) continue;
            const int ql = 4 * g + r;
            if (q == 0) {
                if (c15 == 14) { h_s[w][ql][0] = f2bf(sx); h_s[w][ql][28] = f2bf(sy); }
            } else {
                const int cxq2 = x_dist[SEQ + q] - 14;
                const int cyq2 = y_dist[SEQ + q] - 14;
                if (c15 < 14) {
                    h_s[w][ql][c15 - cxq2 + 14]      = f2bf(px0[r]);
                    h_s[w][ql][28 + c15 - cyq2 + 14] = f2bf(px1[r]);
                } else if (c15 == 14) {
                    h_s[w][ql][0]  = f2bf(px0[r]);
                    h_s[w][ql][28] = f2bf(px1[r]);
                }
            }
        }

        f32x4 o[4];
#pragma unroll
        for (int dt = 0; dt < 4; dt++) o[dt] = (f32x4)0.f;
#pragma unroll
        for (int ks = 0; ks < 7; ks++) {
            bf16x8 pf = *(const bf16x8*)&P_s[(w * 16 + c15) * PP + ks * 32 + g * 8];
#pragma unroll
            for (int dt = 0; dt < 4; dt++) {
                bf16x8 vf = *(const bf16x8*)&VT_s[(dt * 16 + c15) * VP + ks * 32 + g * 8];
                o[dt] = __builtin_amdgcn_mfma_f32_16x16x32_bf16(pf, vf, o[dt], 0, 0, 0);
            }
        }
#pragma unroll
        for (int ks2 = 0; ks2 < 2; ks2++) {
            bf16x8 hf = *(const bf16x8*)&h_s[w][c15][ks2 * 32 + g * 8];
#pragma unroll
            for (int dt = 0; dt < 4; dt++) {
                bf16x8 tf = *(const bf16x8*)&vt_s[(dt * 16 + c15) * TP + ks2 * 32 + g * 8];
                o[dt] = __builtin_amdgcn_mfma_f32_16x16x32_bf16(hf, tf, o[dt], 0, 0, 0);
            }
        }

#pragma unroll
        for (int dt = 0; dt < 4; dt++) {
            const int d = dt * 16 + c15;
#pragma unroll
            for (int r = 0; r < 4; r++) {
                const int q = q4 + r;
                if (q < SEQ)
                    ao[((size_t)(b * SEQ + q)) * EMB + h * HD + d] = f2bf(o[dt][r] * inv[r]);
            }
        }
    }
}

extern "C" void kernel_launch(void* const* d_in, const int* in_sizes, int n_in,
                              void* d_out, int out_size, void* d_ws, size_t ws_size,
                              hipStream_t stream) {
    const float* x       = (const float*)d_in[0];
    const float* Wq      = (const float*)d_in[1];
    const float* bq      = (const float*)d_in[2];
    const float* Wk      = (const float*)d_in[3];
    const float* bk      = (const float*)d_in[4];
    const float* Wv      = (const float*)d_in[5];
    const float* bv      = (const float*)d_in[6];
    const float* Wo      = (const float*)d_in[7];
    const float* bo      = (const float*)d_in[8];
    const float* q_tab_x = (const float*)d_in[9];
    const float* q_tab_y = (const float*)d_in[10];
    const float* v_tab_x = (const float*)d_in[11];
    const float* v_tab_y = (const float*)d_in[12];
    const int*   x_dist  = (const int*)d_in[13];
    const int*   y_dist  = (const int*)d_in[14];
    float* out = (float*)d_out;

    const int M  = in_sizes[0] / EMB;   // 12608
    const int Bc = M / SEQ;             // 64

    ushort* xb   = (ushort*)d_ws;
    ushort* wqkv = xb   + (size_t)M * EMB;
    ushort* wob  = wqkv + (size_t)2304 * EMB;
    ushort* xqb  = wob  + (size_t)EMB * EMB;
    ushort* xkb  = xqb  + (size_t)M * EMB;
    ushort* xvb  = xkb  + (size_t)M * EMB;
    ushort* aob  = xvb  + (size_t)M * EMB;
    ushort* r_o  = aob  + (size_t)M * EMB;

    const int n4x = M * EMB / 4;
    cvt_k<<<dim3((n4x + 255) / 256), dim3(256), 0, stream>>>(x, xb, n4x);
    cvt_w4<<<dim3(2304), dim3(256), 0, stream>>>(Wq, Wk, Wv, Wo, wqkv, wob);

    gemm_k64<0><<<dim3((M + 127) / 128, 18), dim3(256), 0, stream>>>(
        xb, wqkv, bq, bk, bv, xqb, xkb, xvb, nullptr, M);

    rxy_gemm<<<dim3(Bc * NH), dim3(256), 0, stream>>>(xqb, q_tab_x, q_tab_y, r_o);

    attn_mfma<<<dim3(Bc * NH), dim3(NT), 0, stream>>>(
        xqb, xkb, xvb, r_o, v_tab_x, v_tab_y, x_dist, y_dist, aob);

    gemm_k64<1><<<dim3((M + 127) / 128, 6), dim3(256), 0, stream>>>(
        aob, wob, bo, nullptr, nullptr, nullptr, nullptr, nullptr, out, M);
}